// Round 1
// baseline (125.809 us; speedup 1.0000x reference)
//
#include <hip/hip_runtime.h>
#include <math.h>

// Problem constants (fixed by setup_inputs)
#define BB 4
#define TT_LEN 2048
#define INF_ 256   // input features
#define HF 256     // output features
#define MROWS (BB*TT_LEN)     // 8192
#define MN ((size_t)MROWS*HF) // 2097152 per tensor
#define NCHUNK 16
#define TROWS (TT_LEN/NCHUNK) // 128
#define HALF 16
#define TTILE 32
#define NT (TT_LEN/TTILE)     // 64
#define SCALE 0.0625f
#define EPSV 1e-5f

// ws layout (floats):
//  [0, MN)            q
//  [MN, 2MN)          k
//  [2MN, 3MN)         v
//  [3MN, +98304)      partial stats [3][B][NCHUNK][2][H]
//  [.., +6144)        stats [3][B][2][H]  (mean, rstd)
//  [.., +65536)       pout  [B][NT][H]
// total ~24.65 MiB

#define OFF_Q   ((size_t)0)
#define OFF_K   (MN)
#define OFF_V   (2*MN)
#define OFF_PART (3*MN)
#define OFF_STATS (3*MN + (size_t)3*BB*NCHUNK*2*HF)
#define OFF_POUT  (OFF_STATS + (size_t)3*BB*2*HF)

// ---------------- QKV GEMM: out[m][n] = sum_k x[m][k]*W[n][k] + b[n] ----------------
__global__ __launch_bounds__(256) void qkv_gemm_kernel(
    const float* __restrict__ x,
    const float* __restrict__ Wq, const float* __restrict__ bq,
    const float* __restrict__ Wk, const float* __restrict__ bk,
    const float* __restrict__ Wv, const float* __restrict__ bv,
    float* __restrict__ ws)
{
    int which = blockIdx.z;
    const float* Wm   = which == 0 ? Wq : (which == 1 ? Wk : Wv);
    const float* bias = which == 0 ? bq : (which == 1 ? bk : bv);
    float* out = ws + (size_t)which * MN;

    int m0 = blockIdx.x * 64;
    int n0 = blockIdx.y * 64;

    __shared__ float Xs[64][65];
    __shared__ float Wsh[64][65];

    int tid = threadIdx.x;
    int tx = tid & 15, ty = tid >> 4;

    float acc[4][4] = {};

    for (int k0 = 0; k0 < INF_; k0 += 64) {
        int col = (tid & 15) * 4;
        int rbase = tid >> 4;
        #pragma unroll
        for (int i = 0; i < 4; i++) {
            int row = rbase + i * 16;
            float4 xv = *(const float4*)(x + (size_t)(m0 + row) * INF_ + k0 + col);
            Xs[row][col+0] = xv.x; Xs[row][col+1] = xv.y;
            Xs[row][col+2] = xv.z; Xs[row][col+3] = xv.w;
            float4 wv = *(const float4*)(Wm + (size_t)(n0 + row) * INF_ + k0 + col);
            Wsh[row][col+0] = wv.x; Wsh[row][col+1] = wv.y;
            Wsh[row][col+2] = wv.z; Wsh[row][col+3] = wv.w;
        }
        __syncthreads();
        #pragma unroll 8
        for (int kk = 0; kk < 64; kk++) {
            float a[4], bvv[4];
            #pragma unroll
            for (int i = 0; i < 4; i++) a[i] = Xs[ty*4+i][kk];
            #pragma unroll
            for (int j = 0; j < 4; j++) bvv[j] = Wsh[tx*4+j][kk];
            #pragma unroll
            for (int i = 0; i < 4; i++)
                #pragma unroll
                for (int j = 0; j < 4; j++)
                    acc[i][j] += a[i] * bvv[j];
        }
        __syncthreads();
    }
    #pragma unroll
    for (int i = 0; i < 4; i++) {
        int m = m0 + ty*4 + i;
        #pragma unroll
        for (int j = 0; j < 4; j++) {
            int n = n0 + tx*4 + j;
            out[(size_t)m * HF + n] = acc[i][j] + bias[n];
        }
    }
}

// ---------------- instance-norm stats: partial sums over T chunks ----------------
__global__ __launch_bounds__(256) void stat_partial_kernel(
    const float* __restrict__ ws, float* __restrict__ part)
{
    int blk = blockIdx.x; // which*B*NCHUNK + b*NCHUNK + chunk
    int which = blk / (BB * NCHUNK);
    int rem = blk % (BB * NCHUNK);
    int b = rem / NCHUNK, chunk = rem % NCHUNK;
    int h = threadIdx.x;
    const float* src = ws + (size_t)which * MN + ((size_t)b * TT_LEN + (size_t)chunk * TROWS) * HF + h;
    float s1 = 0.f, s2 = 0.f;
    for (int t = 0; t < TROWS; t++) {
        float y = src[(size_t)t * HF];
        s1 += y; s2 += y * y;
    }
    float* p = part + (size_t)blk * 2 * HF;
    p[h] = s1;
    p[HF + h] = s2;
}

__global__ __launch_bounds__(256) void stat_final_kernel(
    const float* __restrict__ part, float* __restrict__ stats)
{
    int blk = blockIdx.x; // which*B + b
    int h = threadIdx.x;
    float s1 = 0.f, s2 = 0.f;
    const float* p = part + (size_t)blk * NCHUNK * 2 * HF;
    for (int c = 0; c < NCHUNK; c++) {
        s1 += p[(size_t)(c*2) * HF + h];
        s2 += p[(size_t)(c*2+1) * HF + h];
    }
    float mean = s1 / TT_LEN;
    float var  = s2 / TT_LEN - mean * mean;
    float rstd = 1.0f / sqrtf(var + EPSV);
    stats[(size_t)blk * 2 * HF + h] = mean;
    stats[(size_t)blk * 2 * HF + HF + h] = rstd;
}

// ---------------- banded attention tile + column-sum PV + partial mean ----------------
__global__ __launch_bounds__(256) void attn_kernel(
    const float* __restrict__ ws, const float* __restrict__ stats,
    float* __restrict__ pout)
{
    int b = blockIdx.x;
    int tile = blockIdx.y;
    int t0 = tile * TTILE;

    const float* q = ws + OFF_Q;
    const float* k = ws + OFF_K;
    const float* v = ws + OFF_V;
    const float* st_q = stats + ((size_t)(0*BB + b) * 2) * HF;
    const float* st_k = stats + ((size_t)(1*BB + b) * 2) * HF;
    const float* st_v = stats + ((size_t)(2*BB + b) * 2) * HF;

    __shared__ float Qs[TTILE][65];
    __shared__ float Ks[64][65];
    __shared__ float Ps[TTILE][64];
    __shared__ float csum[64];

    int tid = threadIdx.x;
    int r  = tid >> 3;        // 0..31 score row
    int c0 = (tid & 7) * 8;   // score col base

    float acc[8] = {};

    for (int k0 = 0; k0 < HF; k0 += 64) {
        // Q chunk: 32x64, normalized
        #pragma unroll
        for (int i = 0; i < 8; i++) {
            int idx = tid + i * 256;
            int qr = idx >> 6, qc = idx & 63;
            int hcol = k0 + qc;
            float y = q[((size_t)(b * TT_LEN + t0 + qr)) * HF + hcol];
            Qs[qr][qc] = (y - st_q[hcol]) * st_q[HF + hcol];
        }
        // K chunk: 64x64 (key rows t0-16 .. t0+47), normalized, OOB -> 0
        #pragma unroll
        for (int i = 0; i < 16; i++) {
            int idx = tid + i * 256;
            int kr = idx >> 6, kc = idx & 63;
            int gt = t0 - HALF + kr;
            int hcol = k0 + kc;
            float y = 0.f;
            if (gt >= 0 && gt < TT_LEN)
                y = (k[((size_t)(b * TT_LEN + gt)) * HF + hcol] - st_k[hcol]) * st_k[HF + hcol];
            Ks[kr][kc] = y;
        }
        __syncthreads();
        #pragma unroll 8
        for (int kk = 0; kk < 64; kk++) {
            float qv = Qs[r][kk];
            #pragma unroll
            for (int j = 0; j < 8; j++)
                acc[j] += qv * Ks[c0 + j][kk];
        }
        __syncthreads();
    }

    // mask + scale; softmax across the 8 lanes owning this row
    float sv[8];
    float mx = -1e30f;
    #pragma unroll
    for (int j = 0; j < 8; j++) {
        int c = c0 + j;
        int gt = t0 - HALF + c;
        bool valid = (c >= r) && (c <= r + 32) && (gt >= 0) && (gt < TT_LEN);
        sv[j] = valid ? acc[j] * SCALE : -1e30f;
        mx = fmaxf(mx, sv[j]);
    }
    #pragma unroll
    for (int d = 1; d < 8; d <<= 1) mx = fmaxf(mx, __shfl_xor(mx, d, 64));
    float sum = 0.f;
    #pragma unroll
    for (int j = 0; j < 8; j++) { sv[j] = expf(sv[j] - mx); sum += sv[j]; }
    #pragma unroll
    for (int d = 1; d < 8; d <<= 1) sum += __shfl_xor(sum, d, 64);
    float inv = 1.0f / sum;
    #pragma unroll
    for (int j = 0; j < 8; j++) Ps[r][c0 + j] = sv[j] * inv;
    __syncthreads();

    // column sums of P (output only needs mean over t!)
    if (tid < 64) {
        float s = 0.f;
        for (int rr = 0; rr < TTILE; rr++) s += Ps[rr][tid];
        csum[tid] = s;
    }
    __syncthreads();

    // weighted sum of normalized v rows; thread = feature h
    int h = tid;
    float mv = st_v[h], rv = st_v[HF + h];
    float o = 0.f;
    for (int c = 0; c < 64; c++) {
        int gt = t0 - HALF + c;
        int gtc = gt < 0 ? 0 : (gt >= TT_LEN ? TT_LEN - 1 : gt);
        float vv = (v[((size_t)(b * TT_LEN + gtc)) * HF + h] - mv) * rv;
        o += csum[c] * vv;   // csum==0 where gt invalid
    }
    pout[((size_t)b * NT + tile) * HF + h] = o;
}

__global__ __launch_bounds__(256) void final_kernel(
    const float* __restrict__ pout, float* __restrict__ out)
{
    int b = blockIdx.x;
    int h = threadIdx.x;
    float s = 0.f;
    for (int tl = 0; tl < NT; tl++)
        s += pout[((size_t)b * NT + tl) * HF + h];
    out[(size_t)b * HF + h] = s * (1.0f / TT_LEN);
}

extern "C" void kernel_launch(void* const* d_in, const int* in_sizes, int n_in,
                              void* d_out, int out_size, void* d_ws, size_t ws_size,
                              hipStream_t stream) {
    const float* x  = (const float*)d_in[0];
    const float* Wq = (const float*)d_in[1];
    const float* bq = (const float*)d_in[2];
    const float* Wk = (const float*)d_in[3];
    const float* bk = (const float*)d_in[4];
    const float* Wv = (const float*)d_in[5];
    const float* bv = (const float*)d_in[6];
    float* out = (float*)d_out;
    float* ws = (float*)d_ws;

    // 1) q,k,v projections
    qkv_gemm_kernel<<<dim3(MROWS/64, HF/64, 3), 256, 0, stream>>>(
        x, Wq, bq, Wk, bk, Wv, bv, ws);
    // 2) instance-norm partial stats
    stat_partial_kernel<<<dim3(3*BB*NCHUNK), 256, 0, stream>>>(ws, ws + OFF_PART);
    // 3) finalize stats
    stat_final_kernel<<<dim3(3*BB), 256, 0, stream>>>(ws + OFF_PART, ws + OFF_STATS);
    // 4) banded attention tiles -> per-tile partial output
    attn_kernel<<<dim3(BB, NT), 256, 0, stream>>>(ws, ws + OFF_STATS, ws + OFF_POUT);
    // 5) mean over tiles
    final_kernel<<<dim3(BB), 256, 0, stream>>>(ws + OFF_POUT, out);
}

// Round 2
// 42.935 us; speedup vs baseline: 2.9302x; 2.9302x over previous
//
#include <hip/hip_runtime.h>
#include <math.h>

#define BB 4
#define TT 2048
#define DIM 256
#define MROWS (BB*TT)               // 8192
#define MN ((size_t)MROWS*DIM)      // 2097152 elements per tensor
#define NTOT 768
#define SCALE 0.0625f
#define HALF 16

typedef __attribute__((ext_vector_type(8))) short short8;
typedef __attribute__((ext_vector_type(4))) float f32x4;
typedef __attribute__((ext_vector_type(4))) unsigned short ushort4v;
typedef __attribute__((ext_vector_type(8))) unsigned short ushort8v;

__device__ __forceinline__ ushort f2bf(float f) {
    unsigned u = __builtin_bit_cast(unsigned, f);
    u += 0x7fffu + ((u >> 16) & 1u);
    return (ushort)(u >> 16);
}
__device__ __forceinline__ float bf2f(ushort u) {
    return __builtin_bit_cast(float, (unsigned)u << 16);
}

#define GLOAD16(g, l) __builtin_amdgcn_global_load_lds( \
    (const __attribute__((address_space(1))) void*)(g), \
    (__attribute__((address_space(3))) void*)(l), 16, 0, 0)

// ---------------- converts ----------------
__global__ __launch_bounds__(256) void convert_x_kernel(const float* __restrict__ x,
                                                        ushort* __restrict__ xbf) {
    int idx = blockIdx.x * 256 + threadIdx.x;      // float4 index, 524288 total
    f32x4 v = *(const f32x4*)(x + (size_t)idx * 4);
    ushort4v o;
    o[0] = f2bf(v[0]); o[1] = f2bf(v[1]); o[2] = f2bf(v[2]); o[3] = f2bf(v[3]);
    *(ushort4v*)(xbf + (size_t)idx * 4) = o;
}

__global__ __launch_bounds__(256) void convert_w_kernel(const float* __restrict__ Wq,
                                                        const float* __restrict__ Wk,
                                                        const float* __restrict__ Wv,
                                                        ushort* __restrict__ wbf) {
    int idx = blockIdx.x * 256 + threadIdx.x;      // float4 index, 49152 total
    int row = idx >> 6, c4 = idx & 63;
    const float* W = row < 256 ? Wq : (row < 512 ? Wk : Wv);
    int r = row & 255;
    f32x4 v = *(const f32x4*)(W + (size_t)r * 256 + c4 * 4);
    ushort4v o;
    o[0] = f2bf(v[0]); o[1] = f2bf(v[1]); o[2] = f2bf(v[2]); o[3] = f2bf(v[3]);
    *(ushort4v*)(wbf + (size_t)idx * 4) = o;
}

__global__ __launch_bounds__(256) void zero_stats_kernel(float* __restrict__ p) {
    p[blockIdx.x * 256 + threadIdx.x] = 0.f;       // 6144 floats
}

// ---------------- MFMA GEMM: qkv = bf16( x @ Wcat^T + bias ), + stat partials ----------------
// C[m][n] = sum_k A[m][k] * B[n][k];  A=xbf row-major K-contig, B=wbf row-major K-contig.
// BM=BN=128, BK=64, 4 waves 2x2, each wave 64x64 = 4x4 frags of 16x16x32.
__global__ __launch_bounds__(256) void gemm_kernel(
    const ushort* __restrict__ xbf, const ushort* __restrict__ wbf,
    const float* __restrict__ bq, const float* __restrict__ bk, const float* __restrict__ bv,
    ushort* __restrict__ qkv, float* __restrict__ statacc)
{
    __shared__ ushort As[128 * 64];   // [row][k] bf16, 16B slots XOR-swizzled by (row&7)
    __shared__ ushort Bs[128 * 64];

    int tid = threadIdx.x;
    int lane = tid & 63, w = tid >> 6;
    int wr = w >> 1, wc = w & 1;
    int m0 = blockIdx.x * 128, n0 = blockIdx.y * 128;

    f32x4 acc[4][4] = {};

    // staging: wave w stages rows [w*32, w*32+32) of both tiles, 8 rows per inst.
    int srow = lane >> 3;                 // 0..7 row within 8-row group
    int sslot = (lane & 7) ^ srow;        // pre-swizzled global 16B-slot
    const ushort* aSrc = xbf + (size_t)(m0 + w * 32 + srow) * DIM + sslot * 8;
    const ushort* bSrc = wbf + (size_t)(n0 + w * 32 + srow) * DIM + sslot * 8;
    ushort* aDst = &As[(w * 32) * 64];
    ushort* bDst = &Bs[(w * 32) * 64];

    int rA = wr * 64 + (lane & 15);
    int rB = wc * 64 + (lane & 15);
    int slotp = lane >> 4;
    int swz = lane & 7;

    for (int kt = 0; kt < 4; kt++) {
        int ko = kt * 64;
        #pragma unroll
        for (int i8 = 0; i8 < 4; i8++) {
            GLOAD16(aSrc + (size_t)i8 * 8 * DIM + ko, aDst + i8 * 8 * 64);
            GLOAD16(bSrc + (size_t)i8 * 8 * DIM + ko, bDst + i8 * 8 * 64);
        }
        __syncthreads();

        short8 a[4][2], b[4][2];
        #pragma unroll
        for (int i = 0; i < 4; i++)
            #pragma unroll
            for (int ks = 0; ks < 2; ks++) {
                int row = rA + i * 16;
                int slot = ks * 4 + slotp;
                a[i][ks] = *(const short8*)(&As[row * 64 + ((slot ^ swz) << 3)]);
            }
        #pragma unroll
        for (int j = 0; j < 4; j++)
            #pragma unroll
            for (int ks = 0; ks < 2; ks++) {
                int row = rB + j * 16;
                int slot = ks * 4 + slotp;
                b[j][ks] = *(const short8*)(&Bs[row * 64 + ((slot ^ swz) << 3)]);
            }
        #pragma unroll
        for (int i = 0; i < 4; i++)
            #pragma unroll
            for (int j = 0; j < 4; j++)
                #pragma unroll
                for (int ks = 0; ks < 2; ks++)
                    acc[i][j] = __builtin_amdgcn_mfma_f32_16x16x32_bf16(
                        a[i][ks], b[j][ks], acc[i][j], 0, 0, 0);
        __syncthreads();
    }

    // epilogue: bias, round to bf16, store, and per-column stat partials
    int b_idx = blockIdx.x >> 4;          // 16 m-blocks per batch
    #pragma unroll
    for (int j = 0; j < 4; j++) {
        int col = n0 + wc * 64 + j * 16 + (lane & 15);
        int which = col >> 8, h = col & 255;
        const float* bias = which == 0 ? bq : (which == 1 ? bk : bv);
        float bb = bias[h];
        float s1 = 0.f, s2 = 0.f;
        ushort* outbase = qkv + (size_t)which * MN + h;
        #pragma unroll
        for (int i = 0; i < 4; i++) {
            #pragma unroll
            for (int rr = 0; rr < 4; rr++) {
                int row = m0 + wr * 64 + i * 16 + (lane >> 4) * 4 + rr;
                float y = acc[i][j][rr] + bb;
                ushort ub = f2bf(y);
                outbase[(size_t)row * DIM] = ub;
                float yr = bf2f(ub);
                s1 += yr; s2 += yr * yr;
            }
        }
        s1 += __shfl_xor(s1, 16, 64); s1 += __shfl_xor(s1, 32, 64);
        s2 += __shfl_xor(s2, 16, 64); s2 += __shfl_xor(s2, 32, 64);
        if ((lane >> 4) == 0) {
            float* sa = statacc + ((size_t)(which * BB + b_idx)) * 512 + h;
            atomicAdd(sa, s1);
            atomicAdd(sa + 256, s2);
        }
    }
}

__global__ __launch_bounds__(256) void stat_final_kernel(const float* __restrict__ acc,
                                                         float* __restrict__ stats) {
    int blk = blockIdx.x;                 // which*BB + b, 12 blocks
    int h = threadIdx.x;
    float s1 = acc[blk * 512 + h], s2 = acc[blk * 512 + 256 + h];
    float mean = s1 * (1.f / 2048.f);
    float var = s2 * (1.f / 2048.f) - mean * mean;
    float rstd = 1.f / sqrtf(var + 1e-5f);
    stats[blk * 512 + h] = mean;
    stats[blk * 512 + 256 + h] = rstd;
}

// ---------------- banded attention, MFMA QK^T, column-sum PV ----------------
__global__ __launch_bounds__(256) void attn_kernel(const ushort* __restrict__ qkv,
                                                   const float* __restrict__ stats,
                                                   float* __restrict__ pout)
{
    int b = blockIdx.x, tile = blockIdx.y;
    int t0 = tile * 32;
    const ushort* qg = qkv;
    const ushort* kg = qkv + MN;
    const ushort* vg = qkv + 2 * MN;
    const float* stq = stats + (size_t)(0 * BB + b) * 512;   // mean @0, rstd @256
    const float* stk = stats + (size_t)(1 * BB + b) * 512;
    const float* stv = stats + (size_t)(2 * BB + b) * 512;

    __shared__ ushort Qs[32 * 256];   // normalized q, bf16, swizzled 16B slots (32/row)
    __shared__ ushort Ks[64 * 256];
    __shared__ float Ps[32][65];
    __shared__ float csum[64];

    int tid = threadIdx.x;

    // stage Q (32x256): 1024 16B-slots, 4 per thread
    #pragma unroll
    for (int i = 0; i < 4; i++) {
        int idx = tid + i * 256;
        int qr = idx >> 5, s = idx & 31;
        int h0 = s * 8;
        ushort8v raw = *(const ushort8v*)(qg + ((size_t)(b * TT + t0 + qr)) * DIM + h0);
        ushort8v o;
        #pragma unroll
        for (int e = 0; e < 8; e++)
            o[e] = f2bf((bf2f(raw[e]) - stq[h0 + e]) * stq[256 + h0 + e]);
        *(ushort8v*)(&Qs[qr * 256 + ((s ^ (qr & 7)) << 3)]) = o;
    }
    // stage K (64x256), key rows t0-16 .. t0+47, OOB -> 0
    #pragma unroll
    for (int i = 0; i < 8; i++) {
        int idx = tid + i * 256;
        int kr = idx >> 5, s = idx & 31;
        int gt = t0 - HALF + kr;
        int h0 = s * 8;
        ushort8v o;
        if (gt >= 0 && gt < TT) {
            ushort8v raw = *(const ushort8v*)(kg + ((size_t)(b * TT + gt)) * DIM + h0);
            #pragma unroll
            for (int e = 0; e < 8; e++)
                o[e] = f2bf((bf2f(raw[e]) - stk[h0 + e]) * stk[256 + h0 + e]);
        } else {
            #pragma unroll
            for (int e = 0; e < 8; e++) o[e] = 0;
        }
        *(ushort8v*)(&Ks[kr * 256 + ((s ^ (kr & 7)) << 3)]) = o;
    }
    __syncthreads();

    // MFMA scores: 32x64 tile = 2 row-frags x 4 col-frags; wave w owns col-frag w
    int lane = tid & 63, w = tid >> 6;
    f32x4 sacc[2] = {};
    int arow0 = lane & 15;
    int brow = w * 16 + (lane & 15);
    int slotp = lane >> 4;
    int swz = lane & 7;
    #pragma unroll
    for (int ks = 0; ks < 8; ks++) {
        int slot = ks * 4 + slotp;
        short8 bf = *(const short8*)(&Ks[brow * 256 + ((slot ^ swz) << 3)]);
        #pragma unroll
        for (int rf = 0; rf < 2; rf++) {
            int arow = rf * 16 + arow0;
            short8 af = *(const short8*)(&Qs[arow * 256 + ((slot ^ swz) << 3)]);
            sacc[rf] = __builtin_amdgcn_mfma_f32_16x16x32_bf16(af, bf, sacc[rf], 0, 0, 0);
        }
    }
    #pragma unroll
    for (int rf = 0; rf < 2; rf++)
        #pragma unroll
        for (int rr = 0; rr < 4; rr++)
            Ps[rf * 16 + (lane >> 4) * 4 + rr][w * 16 + (lane & 15)] = sacc[rf][rr];
    __syncthreads();

    // softmax: thread (r = tid>>3) owns cols c0..c0+7
    int r = tid >> 3, c0 = (tid & 7) * 8;
    float sv[8];
    float mx = -1e30f;
    #pragma unroll
    for (int j = 0; j < 8; j++) {
        int c = c0 + j;
        int gt = t0 - HALF + c;
        bool valid = (c >= r) && (c <= r + 32) && (gt >= 0) && (gt < TT);
        sv[j] = valid ? Ps[r][c] * SCALE : -1e30f;
        mx = fmaxf(mx, sv[j]);
    }
    #pragma unroll
    for (int d = 1; d < 8; d <<= 1) mx = fmaxf(mx, __shfl_xor(mx, d, 64));
    float sum = 0.f;
    #pragma unroll
    for (int j = 0; j < 8; j++) { sv[j] = __expf(sv[j] - mx); sum += sv[j]; }
    #pragma unroll
    for (int d = 1; d < 8; d <<= 1) sum += __shfl_xor(sum, d, 64);
    float inv = 1.0f / sum;
    #pragma unroll
    for (int j = 0; j < 8; j++) Ps[r][c0 + j] = sv[j] * inv;
    __syncthreads();

    // column sums of P
    if (tid < 64) {
        float s = 0.f;
        #pragma unroll 8
        for (int rr = 0; rr < 32; rr++) s += Ps[rr][tid];
        csum[tid] = s;
    }
    __syncthreads();

    // weighted sum of normalized v rows; thread = feature h
    int h = tid;
    float mv = stv[h], rv = stv[256 + h];
    float o = 0.f;
    for (int c = 0; c < 64; c++) {
        int gt = t0 - HALF + c;
        int gtc = gt < 0 ? 0 : (gt >= TT ? TT - 1 : gt);
        float vv = (bf2f(vg[((size_t)(b * TT + gtc)) * DIM + h]) - mv) * rv;
        o += csum[c] * vv;
    }
    pout[((size_t)b * 64 + tile) * DIM + h] = o;
}

__global__ __launch_bounds__(256) void final_kernel(const float* __restrict__ pout,
                                                    float* __restrict__ out) {
    int b = blockIdx.x;
    int h = threadIdx.x;
    float s = 0.f;
    #pragma unroll 8
    for (int tl = 0; tl < 64; tl++)
        s += pout[((size_t)b * 64 + tl) * DIM + h];
    out[(size_t)b * DIM + h] = s * (1.0f / TT);
}

extern "C" void kernel_launch(void* const* d_in, const int* in_sizes, int n_in,
                              void* d_out, int out_size, void* d_ws, size_t ws_size,
                              hipStream_t stream) {
    const float* x  = (const float*)d_in[0];
    const float* Wq = (const float*)d_in[1];
    const float* bq = (const float*)d_in[2];
    const float* Wk = (const float*)d_in[3];
    const float* bk = (const float*)d_in[4];
    const float* Wv = (const float*)d_in[5];
    const float* bv = (const float*)d_in[6];
    float* out = (float*)d_out;

    ushort* qkv = (ushort*)d_ws;                       // 3*MN ushorts (12.6 MB)
    ushort* xbf = qkv + 3 * MN;                        // MN ushorts (4.2 MB)
    ushort* wbf = xbf + MN;                            // 768*256 ushorts
    float* statacc = (float*)(wbf + (size_t)NTOT * DIM);  // 6144 floats (atomic sums)
    float* stats   = statacc + 6144;                   // 6144 floats (mean/rstd)
    float* pout    = stats + 6144;                     // 65536 floats

    convert_x_kernel<<<2048, 256, 0, stream>>>(x, xbf);
    convert_w_kernel<<<192, 256, 0, stream>>>(Wq, Wk, Wv, wbf);
    zero_stats_kernel<<<24, 256, 0, stream>>>(statacc);
    gemm_kernel<<<dim3(MROWS / 128, NTOT / 128), 256, 0, stream>>>(
        xbf, wbf, bq, bk, bv, qkv, statacc);
    stat_final_kernel<<<12, 256, 0, stream>>>(statacc, stats);
    attn_kernel<<<dim3(BB, TT / 32), 256, 0, stream>>>(qkv, stats, pout);
    final_kernel<<<BB, 256, 0, stream>>>(pout, out);
}

// Round 3
// 31.857 us; speedup vs baseline: 3.9492x; 1.3477x over previous
//
#include <hip/hip_runtime.h>
#include <math.h>

#define BB 4
#define TT 2048
#define DIM 256
#define MROWS (BB*TT)               // 8192
#define MN ((size_t)MROWS*DIM)      // 2097152 elements per tensor
#define NTOT 768
#define SCALE 0.0625f
#define HALF 16

typedef __attribute__((ext_vector_type(8))) short short8;
typedef __attribute__((ext_vector_type(4))) float f32x4;
typedef __attribute__((ext_vector_type(4))) unsigned short ushort4v;
typedef __attribute__((ext_vector_type(8))) unsigned short ushort8v;

__device__ __forceinline__ ushort f2bf(float f) {
    unsigned u = __builtin_bit_cast(unsigned, f);
    u += 0x7fffu + ((u >> 16) & 1u);
    return (ushort)(u >> 16);
}
__device__ __forceinline__ float bf2f(ushort u) {
    return __builtin_bit_cast(float, (unsigned)u << 16);
}

#define GLOAD16(g, l) __builtin_amdgcn_global_load_lds( \
    (const __attribute__((address_space(1))) void*)(g), \
    (__attribute__((address_space(3))) void*)(l), 16, 0, 0)

// ---------------- prep: x->bf16, W->bf16, zero stat accumulators ----------------
__global__ __launch_bounds__(256) void prep_kernel(
    const float* __restrict__ x,
    const float* __restrict__ Wq, const float* __restrict__ Wk, const float* __restrict__ Wv,
    ushort* __restrict__ xbf, ushort* __restrict__ wbf, float* __restrict__ statacc)
{
    int bid = blockIdx.x, tid = threadIdx.x;
    if (bid < 2048) {
        int idx = bid * 256 + tid;                    // float4 index
        f32x4 v = *(const f32x4*)(x + (size_t)idx * 4);
        ushort4v o;
        o[0] = f2bf(v[0]); o[1] = f2bf(v[1]); o[2] = f2bf(v[2]); o[3] = f2bf(v[3]);
        *(ushort4v*)(xbf + (size_t)idx * 4) = o;
    } else if (bid < 2240) {
        int idx = (bid - 2048) * 256 + tid;
        int row = idx >> 6, c4 = idx & 63;
        const float* W = row < 256 ? Wq : (row < 512 ? Wk : Wv);
        int r = row & 255;
        f32x4 v = *(const f32x4*)(W + (size_t)r * 256 + c4 * 4);
        ushort4v o;
        o[0] = f2bf(v[0]); o[1] = f2bf(v[1]); o[2] = f2bf(v[2]); o[3] = f2bf(v[3]);
        *(ushort4v*)(wbf + (size_t)idx * 4) = o;
    } else {
        #pragma unroll
        for (int i = 0; i < 24; i++) statacc[i * 256 + tid] = 0.f;  // 6144 floats
    }
}

// ---------------- MFMA GEMM: qkv = bf16( x @ Wcat^T + bias ), + stat partials ----------------
// BM=64, BN=128, BK=64; grid 128x6 = 768 blocks = exactly 3/CU.
// 4 waves 2x2; wave tile 32x64 = 2x4 frags of 16x16x32. Double-buffered 2-phase.
#define A_TILE (64*64)
#define B_TILE (128*64)
__global__ __launch_bounds__(256) void gemm_kernel(
    const ushort* __restrict__ xbf, const ushort* __restrict__ wbf,
    const float* __restrict__ bq, const float* __restrict__ bk, const float* __restrict__ bv,
    ushort* __restrict__ qkv, float* __restrict__ statacc)
{
    __shared__ ushort As[2 * A_TILE];
    __shared__ ushort Bs[2 * B_TILE];

    int tid = threadIdx.x;
    int lane = tid & 63, w = tid >> 6;
    int wr = w >> 1, wc = w & 1;

    // XCD-aware remap: 768 blocks, 8 XCDs, 96/XCD; n-fastest so each XCD
    // keeps a contiguous 16-tile A panel (0.5 MB) + all of B in its L2.
    int orig = blockIdx.x + blockIdx.y * 128;
    int wg = (orig & 7) * 96 + (orig >> 3);
    int mb = wg / 6, nb = wg % 6;
    int m0 = mb * 64, n0 = nb * 128;

    f32x4 acc[2][4] = {};

    // staging: A rows w*16..+16 (2 insts), B rows w*32..+32 (4 insts); 8 rows/inst.
    int srow = lane >> 3;                 // 0..7
    int scol = (lane & 7) ^ srow;         // pre-swizzled 16B slot
    const ushort* aSrc = xbf + (size_t)(m0 + w * 16 + srow) * DIM + scol * 8;
    const ushort* bSrc = wbf + (size_t)(n0 + w * 32 + srow) * DIM + scol * 8;
    int aOff = (w * 16) * 64;
    int bOff = (w * 32) * 64;

    auto stage = [&](int buf, int kt) {
        int ko = kt * 64;
        #pragma unroll
        for (int i = 0; i < 2; i++)
            GLOAD16(aSrc + (size_t)i * 8 * DIM + ko, &As[buf * A_TILE + aOff + i * 8 * 64]);
        #pragma unroll
        for (int i = 0; i < 4; i++)
            GLOAD16(bSrc + (size_t)i * 8 * DIM + ko, &Bs[buf * B_TILE + bOff + i * 8 * 64]);
    };

    int fr = lane & 15, fp = lane >> 4, swz = lane & 7;

    stage(0, 0);
    __syncthreads();                       // compiler emits vmcnt(0) drain
    int cur = 0;
    for (int kt = 0; kt < 4; kt++) {
        if (kt < 3) stage(cur ^ 1, kt + 1);    // prefetch overlaps MFMA below
        const ushort* a_lds = &As[cur * A_TILE];
        const ushort* b_lds = &Bs[cur * B_TILE];
        short8 a[2][2], b[4][2];
        #pragma unroll
        for (int i = 0; i < 2; i++)
            #pragma unroll
            for (int ks = 0; ks < 2; ks++) {
                int row = wr * 32 + i * 16 + fr;
                int slot = ks * 4 + fp;
                a[i][ks] = *(const short8*)(&a_lds[row * 64 + ((slot ^ swz) << 3)]);
            }
        #pragma unroll
        for (int j = 0; j < 4; j++)
            #pragma unroll
            for (int ks = 0; ks < 2; ks++) {
                int row = wc * 64 + j * 16 + fr;
                int slot = ks * 4 + fp;
                b[j][ks] = *(const short8*)(&b_lds[row * 64 + ((slot ^ swz) << 3)]);
            }
        #pragma unroll
        for (int i = 0; i < 2; i++)
            #pragma unroll
            for (int j = 0; j < 4; j++)
                #pragma unroll
                for (int ks = 0; ks < 2; ks++)
                    acc[i][j] = __builtin_amdgcn_mfma_f32_16x16x32_bf16(
                        a[i][ks], b[j][ks], acc[i][j], 0, 0, 0);
        __syncthreads();                   // drains prefetch vmcnt + lgkm
        cur ^= 1;
    }

    // epilogue: bias, round to bf16, store, per-column stat partials
    int b_idx = mb >> 5;                   // 32 m-blocks per batch
    #pragma unroll
    for (int j = 0; j < 4; j++) {
        int col = n0 + wc * 64 + j * 16 + fr;
        int which = col >> 8, h = col & 255;
        const float* bias = which == 0 ? bq : (which == 1 ? bk : bv);
        float bb = bias[h];
        float s1 = 0.f, s2 = 0.f;
        ushort* outbase = qkv + (size_t)which * MN + h;
        #pragma unroll
        for (int i = 0; i < 2; i++) {
            #pragma unroll
            for (int rr = 0; rr < 4; rr++) {
                int row = m0 + wr * 32 + i * 16 + fp * 4 + rr;
                float y = acc[i][j][rr] + bb;
                ushort ub = f2bf(y);
                outbase[(size_t)row * DIM] = ub;
                float yr = bf2f(ub);
                s1 += yr; s2 += yr * yr;
            }
        }
        s1 += __shfl_xor(s1, 16, 64); s1 += __shfl_xor(s1, 32, 64);
        s2 += __shfl_xor(s2, 16, 64); s2 += __shfl_xor(s2, 32, 64);
        if (fp == 0) {
            float* sa = statacc + ((size_t)(which * BB + b_idx)) * 512 + h;
            atomicAdd(sa, s1);
            atomicAdd(sa + 256, s2);
        }
    }
}

// ---------------- banded attention: inline stats, MFMA QK^T, column-sum PV ----------------
__global__ __launch_bounds__(256) void attn_kernel(const ushort* __restrict__ qkv,
                                                   const float* __restrict__ statacc,
                                                   float* __restrict__ pout)
{
    // grid (64,4): x=tile, y=b; XCD remap keeps contiguous tile ranges per XCD
    int orig = blockIdx.x + blockIdx.y * 64;
    int wg = (orig & 7) * 32 + (orig >> 3);
    int tile = wg & 63, b = wg >> 6;
    int t0 = tile * 32;

    const ushort* qg = qkv;
    const ushort* kg = qkv + MN;
    const ushort* vg = qkv + 2 * MN;

    __shared__ ushort Qs[32 * 256];
    __shared__ ushort Ks[64 * 256];
    __shared__ float Ps[32][65];
    __shared__ float csum[64];
    __shared__ float nsc[3][256], nsh[3][256];   // scale=rstd, shift=-mean*rstd

    int tid = threadIdx.x;

    // inline stat finalize (was stat_final_kernel)
    #pragma unroll
    for (int which = 0; which < 3; which++) {
        float s1 = statacc[(size_t)(which * BB + b) * 512 + tid];
        float s2 = statacc[(size_t)(which * BB + b) * 512 + 256 + tid];
        float mean = s1 * (1.f / 2048.f);
        float var  = s2 * (1.f / 2048.f) - mean * mean;
        float rstd = 1.f / sqrtf(var + 1e-5f);
        nsc[which][tid] = rstd;
        nsh[which][tid] = -mean * rstd;
    }
    __syncthreads();

    // stage Q (32x256): 1024 16B-slots, 4/thread, normalized
    #pragma unroll
    for (int i = 0; i < 4; i++) {
        int idx = tid + i * 256;
        int qr = idx >> 5, s = idx & 31;
        int h0 = s * 8;
        ushort8v raw = *(const ushort8v*)(qg + ((size_t)(b * TT + t0 + qr)) * DIM + h0);
        ushort8v o;
        #pragma unroll
        for (int e = 0; e < 8; e++)
            o[e] = f2bf(bf2f(raw[e]) * nsc[0][h0 + e] + nsh[0][h0 + e]);
        *(ushort8v*)(&Qs[qr * 256 + ((s ^ (qr & 7)) << 3)]) = o;
    }
    // stage K (64x256), key rows t0-16 .. t0+47, OOB -> 0
    #pragma unroll
    for (int i = 0; i < 8; i++) {
        int idx = tid + i * 256;
        int kr = idx >> 5, s = idx & 31;
        int gt = t0 - HALF + kr;
        int h0 = s * 8;
        ushort8v o;
        if (gt >= 0 && gt < TT) {
            ushort8v raw = *(const ushort8v*)(kg + ((size_t)(b * TT + gt)) * DIM + h0);
            #pragma unroll
            for (int e = 0; e < 8; e++)
                o[e] = f2bf(bf2f(raw[e]) * nsc[1][h0 + e] + nsh[1][h0 + e]);
        } else {
            #pragma unroll
            for (int e = 0; e < 8; e++) o[e] = 0;
        }
        *(ushort8v*)(&Ks[kr * 256 + ((s ^ (kr & 7)) << 3)]) = o;
    }
    __syncthreads();

    // MFMA scores 32x64: wave w owns col-frag w; 2 row-frags
    int lane = tid & 63, w = tid >> 6;
    f32x4 sacc[2] = {};
    int arow0 = lane & 15;
    int brow = w * 16 + (lane & 15);
    int slotp = lane >> 4;
    int swz = lane & 7;
    #pragma unroll
    for (int ks = 0; ks < 8; ks++) {
        int slot = ks * 4 + slotp;
        short8 bf = *(const short8*)(&Ks[brow * 256 + ((slot ^ swz) << 3)]);
        #pragma unroll
        for (int rf = 0; rf < 2; rf++) {
            int arow = rf * 16 + arow0;
            short8 af = *(const short8*)(&Qs[arow * 256 + ((slot ^ swz) << 3)]);
            sacc[rf] = __builtin_amdgcn_mfma_f32_16x16x32_bf16(af, bf, sacc[rf], 0, 0, 0);
        }
    }
    #pragma unroll
    for (int rf = 0; rf < 2; rf++)
        #pragma unroll
        for (int rr = 0; rr < 4; rr++)
            Ps[rf * 16 + (lane >> 4) * 4 + rr][w * 16 + (lane & 15)] = sacc[rf][rr];
    __syncthreads();

    // softmax: thread (r = tid>>3) owns cols c0..c0+7
    int r = tid >> 3, c0 = (tid & 7) * 8;
    float sv[8];
    float mx = -1e30f;
    #pragma unroll
    for (int j = 0; j < 8; j++) {
        int c = c0 + j;
        int gt = t0 - HALF + c;
        bool valid = (c >= r) && (c <= r + 32) && (gt >= 0) && (gt < TT);
        sv[j] = valid ? Ps[r][c] * SCALE : -1e30f;
        mx = fmaxf(mx, sv[j]);
    }
    #pragma unroll
    for (int d = 1; d < 8; d <<= 1) mx = fmaxf(mx, __shfl_xor(mx, d, 64));
    float sum = 0.f;
    #pragma unroll
    for (int j = 0; j < 8; j++) { sv[j] = __expf(sv[j] - mx); sum += sv[j]; }
    #pragma unroll
    for (int d = 1; d < 8; d <<= 1) sum += __shfl_xor(sum, d, 64);
    float inv = 1.0f / sum;
    #pragma unroll
    for (int j = 0; j < 8; j++) Ps[r][c0 + j] = sv[j] * inv;
    __syncthreads();

    // column sums of P (output only needs mean over t)
    if (tid < 64) {
        float s = 0.f;
        #pragma unroll 8
        for (int rr = 0; rr < 32; rr++) s += Ps[rr][tid];
        csum[tid] = s;
    }
    __syncthreads();

    // weighted sum of normalized v rows; thread = feature h
    int h = tid;
    float vs = nsc[2][h], vh = nsh[2][h];
    float o = 0.f;
    for (int c = 0; c < 64; c++) {
        int gt = t0 - HALF + c;
        int gtc = gt < 0 ? 0 : (gt >= TT ? TT - 1 : gt);
        float vv = bf2f(vg[((size_t)(b * TT + gtc)) * DIM + h]) * vs + vh;
        o += csum[c] * vv;
    }
    pout[((size_t)b * 64 + tile) * DIM + h] = o;
}

__global__ __launch_bounds__(256) void final_kernel(const float* __restrict__ pout,
                                                    float* __restrict__ out) {
    int b = blockIdx.x;
    int h = threadIdx.x;
    float s = 0.f;
    #pragma unroll 8
    for (int tl = 0; tl < 64; tl++)
        s += pout[((size_t)b * 64 + tl) * DIM + h];
    out[(size_t)b * DIM + h] = s * (1.0f / TT);
}

extern "C" void kernel_launch(void* const* d_in, const int* in_sizes, int n_in,
                              void* d_out, int out_size, void* d_ws, size_t ws_size,
                              hipStream_t stream) {
    const float* x  = (const float*)d_in[0];
    const float* Wq = (const float*)d_in[1];
    const float* bq = (const float*)d_in[2];
    const float* Wk = (const float*)d_in[3];
    const float* bk = (const float*)d_in[4];
    const float* Wv = (const float*)d_in[5];
    const float* bv = (const float*)d_in[6];
    float* out = (float*)d_out;

    ushort* qkv = (ushort*)d_ws;                       // 3*MN ushorts
    ushort* xbf = qkv + 3 * MN;                        // MN ushorts
    ushort* wbf = xbf + MN;                            // NTOT*DIM ushorts
    float* statacc = (float*)(wbf + (size_t)NTOT * DIM);  // 6144 floats
    float* pout    = statacc + 6144;                   // 65536 floats

    prep_kernel<<<2241, 256, 0, stream>>>(x, Wq, Wk, Wv, xbf, wbf, statacc);
    gemm_kernel<<<dim3(128, 6), 256, 0, stream>>>(xbf, wbf, bq, bk, bv, qkv, statacc);
    attn_kernel<<<dim3(64, 4), 256, 0, stream>>>(qkv, statacc, pout);
    final_kernel<<<BB, 256, 0, stream>>>(pout, out);
}